// Round 6
// baseline (319.536 us; speedup 1.0000x reference)
//
#include <hip/hip_runtime.h>

#define NREL 32

typedef short short8 __attribute__((ext_vector_type(8)));
typedef float f32x4 __attribute__((ext_vector_type(4)));

__device__ inline unsigned short f2bf(float f) {
    union { float f; unsigned u; } u; u.f = f;
    unsigned r = u.u + 0x7FFF + ((u.u >> 16) & 1);   // RNE
    return (unsigned short)(r >> 16);
}

// Padded-bucket exclusive scan over hist[32], in-register (per-wave).
__device__ inline void bucket_scan(const int* __restrict__ hist, int lane,
                                   int& h, int& P, int& excl) {
    h = (lane < NREL) ? hist[lane] : 0;
    P = ((h + 63) >> 6) << 6;
    int s = P;
    #pragma unroll
    for (int off = 1; off < 32; off <<= 1) {
        int t = __shfl_up(s, off, 64);
        if ((lane & 31) >= off) s += t;
    }
    excl = s - P;
}

// Device-scope counting grid barrier (all blocks co-resident by construction:
// grid = 768 = 3 blocks/CU enforced via __launch_bounds__(256,3), LDS 8.2 KB).
__device__ inline void grid_barrier(int* bar, int target) {
    __syncthreads();
    if (threadIdx.x == 0) {
        __hip_atomic_fetch_add(bar, 1, __ATOMIC_RELEASE, __HIP_MEMORY_SCOPE_AGENT);
        while (__hip_atomic_load(bar, __ATOMIC_ACQUIRE, __HIP_MEMORY_SCOPE_AGENT) < target)
            __builtin_amdgcn_s_sleep(2);
    }
    __syncthreads();
}

// ---------------------------------------------------------------------------
// ws layout:
//   wtb  [2*32*4096] ushort  bf16 normalized tables, TRANSPOSED:
//                            wtb[(dir*32+r)*4096 + o*64 + i]
//   xbf  [N*64] ushort       bf16(x)
//   cntf [N] f32 | cntb [N] f32 | hist [32] | fill [32]   (zeroed in phase 0)
//   bar  [1] int             grid barrier (zeroed by 4-byte memset)
//   einfo[maxC*64] int4      {src, dst, invf_bits, invb_bits} grouped by rel
// ---------------------------------------------------------------------------

__global__ __launch_bounds__(256, 3) void fused_kernel(
        const float* __restrict__ x,
        const int* __restrict__ src, const int* __restrict__ dst,
        const int* __restrict__ et,
        const float* __restrict__ wf, const float* __restrict__ wb,
        const float* __restrict__ lw, const float* __restrict__ lb,
        unsigned short* wtb, unsigned short* xbf,
        float* cntf, float* cntb, int* hist, int* fill,
        int* bar, int4* einfo, float* out,
        int E, int N, int nCountB, int nLinB) {
    __shared__ float smem[4 * 8 * 64 + 8];
    int tid = threadIdx.x;
    int lane = tid & 63;
    const int G = gridDim.x;

    // ================= phase 0: zero cntf,cntb,hist,fill (contiguous) ======
    {
        int tot = 2 * N + 2 * NREL;
        for (int i = blockIdx.x * 256 + tid; i < tot; i += G * 256) cntf[i] = 0.f;
    }
    grid_barrier(bar, G);

    // ================= phase 1: count | norm | linear ======================
    int totalRoles = nCountB + 64 + nLinB;
    for (int b = blockIdx.x; b < totalRoles; b += G) {
        if (b < nCountB) {
            // ---- count role ----
            int* lh = (int*)smem;
            if (tid < NREL) lh[tid] = 0;
            __syncthreads();
            int e = b * 256 + tid;
            if (e < E) {
                atomicAdd(&cntf[src[e]], 1.0f);
                atomicAdd(&cntb[dst[e]], 1.0f);
                atomicAdd(&lh[et[e]], 1);
            }
            __syncthreads();
            if (tid < NREL && lh[tid]) atomicAdd(&hist[tid], lh[tid]);
        } else if (b < nCountB + 64) {
            // ---- norm role: normalize fp32 table row, write bf16 transposed
            int b2 = b - nCountB;
            int rel = b2 & 31, tab = b2 >> 5;
            const float* s_ = (tab ? wb : wf) + rel * 4096;
            unsigned short* d_ = wtb + (size_t)b2 * 4096;
            float* part = smem;
            float ssum = 0.f;
            #pragma unroll
            for (int k = 0; k < 16; k += 4) {
                float4 v = *(const float4*)(s_ + tid * 16 + k);
                ssum += v.x * v.x + v.y * v.y + v.z * v.z + v.w * v.w;
            }
            #pragma unroll
            for (int off = 32; off >= 1; off >>= 1) ssum += __shfl_down(ssum, off, 64);
            if ((tid & 63) == 0) part[tid >> 6] = ssum;
            __syncthreads();
            if (tid == 0) part[4] = 1.0f / (sqrtf(part[0] + part[1] + part[2] + part[3]) + 0.01f);
            __syncthreads();
            float sc = part[4];
            int i = tid >> 2, o0 = (tid & 3) * 16;
            #pragma unroll
            for (int q = 0; q < 4; ++q) {
                float4 v = *(const float4*)(s_ + i * 64 + o0 + q * 4);
                d_[(o0 + q * 4 + 0) * 64 + i] = f2bf(v.x * sc);
                d_[(o0 + q * 4 + 1) * 64 + i] = f2bf(v.y * sc);
                d_[(o0 + q * 4 + 2) * 64 + i] = f2bf(v.z * sc);
                d_[(o0 + q * 4 + 3) * 64 + i] = f2bf(v.w * sc);
            }
        } else {
            // ---- linear + xbf role: 32 nodes per work item ----
            int b3 = b - nCountB - 64;
            int w = tid >> 6;
            int nodeBase = b3 * 32 + w * 8;
            float4 wrow[16];
            const float4* lwrow = (const float4*)(lw + lane * 64);
            #pragma unroll
            for (int g = 0; g < 16; ++g) wrow[g] = lwrow[g];
            float bias = lb[lane];
            float* xs = smem + w * 8 * 64;
            #pragma unroll
            for (int t = 0; t < 8; ++t) {
                int n = nodeBase + t;
                if (n < N) {
                    float v = x[(size_t)n * 64 + lane];
                    xs[t * 64 + lane] = v;
                    xbf[(size_t)n * 64 + lane] = f2bf(v);
                }
            }
            __syncthreads();
            for (int t = 0; t < 8; ++t) {
                int n = nodeBase + t;
                if (n >= N) break;
                float acc = bias;
                const float4* xr = (const float4*)(xs + t * 64);
                #pragma unroll
                for (int g = 0; g < 16; ++g) {
                    float4 xv = xr[g];
                    acc = fmaf(xv.x, wrow[g].x, acc);
                    acc = fmaf(xv.y, wrow[g].y, acc);
                    acc = fmaf(xv.z, wrow[g].z, acc);
                    acc = fmaf(xv.w, wrow[g].w, acc);
                }
                out[(size_t)n * 64 + lane] = acc;
            }
        }
        __syncthreads();   // protect smem reuse across loop iterations
    }
    grid_barrier(bar, 2 * G);

    // ================= phase 2: counting-sort scatter =======================
    {
        int* lh = (int*)smem;            // [0..31]
        int* lbase = lh + NREL;          // [32..63]
        int* bstartS = lh + 2 * NREL;    // [64..95] — stable across iterations
        if (tid < 64) {
            int h2, P2, excl2;
            bucket_scan(hist, tid, h2, P2, excl2);
            if (tid < NREL) bstartS[tid] = excl2;
        }
        __syncthreads();
        for (int b = blockIdx.x; b < nCountB; b += G) {
            if (tid < NREL) lh[tid] = 0;
            __syncthreads();
            int e = b * 256 + tid;
            int r = 0, my = 0;
            bool valid = (e < E);
            if (valid) { r = et[e]; my = atomicAdd(&lh[r], 1); }
            __syncthreads();
            if (tid < NREL && lh[tid]) lbase[tid] = atomicAdd(&fill[tid], lh[tid]);
            __syncthreads();
            if (valid) {
                int s = src[e], d = dst[e];
                float invf = 1.0f / (cntf[s] + 1.0f);
                float invb = 1.0f / (cntb[d] + 1.0f);
                einfo[bstartS[r] + lbase[r] + my] =
                    make_int4(s, d, __float_as_int(invf), __float_as_int(invb));
            }
            __syncthreads();
        }
    }
    grid_barrier(bar, 3 * G);

    // ================= phase 3: MFMA conv (LDS-free, no barriers) ==========
    {
        int h, P, excl;
        bucket_scan(hist, lane, h, P, excl);
        int totChunks = __shfl(excl + P, 31, 64) >> 6;
        int w = tid >> 6, m = lane & 15, quad = (lane >> 4) & 3;

        for (int c = blockIdx.x; c < 2 * totChunks; c += G) {
            int dir = (c >= totChunks);
            int cid = dir ? c - totChunks : c;
            int pos = cid * 64;
            unsigned long long mm = __ballot(lane < NREL && pos >= excl && pos < excl + P);
            int rel = __ffsll(mm) - 1;
            int start = __shfl(excl, rel, 64);
            int hr = __shfl(h, rel, 64);
            int valid = hr - (pos - start);
            if (valid > 64) valid = 64;

            // this lane's A-row = w*16 + m; pad rows clamp to slot 0 (their
            // C rows are simply never written — MFMA rows are independent)
            int row = w * 16 + m;
            int4 v = einfo[pos + (row < valid ? row : 0)];
            int s_ = dir ? v.y : v.x;
            int d_ = dir ? v.x : v.y;
            float inv = __int_as_float(dir ? v.w : v.z);

            const unsigned short* xr = xbf + (size_t)s_ * 64 + quad * 8;
            short8 a0 = *(const short8*)(xr);
            short8 a1 = *(const short8*)(xr + 32);

            const unsigned short* bb = wtb + (size_t)((dir << 5) + rel) * 4096
                                           + m * 64 + quad * 8;
            f32x4 acc0 = {0.f, 0.f, 0.f, 0.f}, acc1 = acc0, acc2 = acc0, acc3 = acc0;
            {
                short8 b0 = *(const short8*)(bb);
                short8 b1 = *(const short8*)(bb + 1024);
                short8 b2 = *(const short8*)(bb + 2048);
                short8 b3 = *(const short8*)(bb + 3072);
                acc0 = __builtin_amdgcn_mfma_f32_16x16x32_bf16(a0, b0, acc0, 0, 0, 0);
                acc1 = __builtin_amdgcn_mfma_f32_16x16x32_bf16(a0, b1, acc1, 0, 0, 0);
                acc2 = __builtin_amdgcn_mfma_f32_16x16x32_bf16(a0, b2, acc2, 0, 0, 0);
                acc3 = __builtin_amdgcn_mfma_f32_16x16x32_bf16(a0, b3, acc3, 0, 0, 0);
            }
            {
                short8 b0 = *(const short8*)(bb + 32);
                short8 b1 = *(const short8*)(bb + 1024 + 32);
                short8 b2 = *(const short8*)(bb + 2048 + 32);
                short8 b3 = *(const short8*)(bb + 3072 + 32);
                acc0 = __builtin_amdgcn_mfma_f32_16x16x32_bf16(a1, b0, acc0, 0, 0, 0);
                acc1 = __builtin_amdgcn_mfma_f32_16x16x32_bf16(a1, b1, acc1, 0, 0, 0);
                acc2 = __builtin_amdgcn_mfma_f32_16x16x32_bf16(a1, b2, acc2, 0, 0, 0);
                acc3 = __builtin_amdgcn_mfma_f32_16x16x32_bf16(a1, b3, acc3, 0, 0, 0);
            }

            // epilogue: C/D layout col=lane&15 (=m), row=quad*4+reg (m89)
            #pragma unroll
            for (int r = 0; r < 4; ++r) {
                int qq = quad * 4 + r;                 // row within this wave's 16
                int dd = __shfl(d_, qq, 64);           // lane qq holds row qq's einfo
                float iv = __shfl(inv, qq, 64);
                if (w * 16 + qq < valid) {
                    float* op = out + (size_t)dd * 64 + m;
                    atomicAdd(op +  0, acc0[r] * iv);
                    atomicAdd(op + 16, acc1[r] * iv);
                    atomicAdd(op + 32, acc2[r] * iv);
                    atomicAdd(op + 48, acc3[r] * iv);
                }
            }
        }
    }
}

extern "C" void kernel_launch(void* const* d_in, const int* in_sizes, int n_in,
                              void* d_out, int out_size, void* d_ws, size_t ws_size,
                              hipStream_t stream) {
    const float* x  = (const float*)d_in[0];
    const int*   ei = (const int*)  d_in[1];
    const int*   et = (const int*)  d_in[2];
    const float* wf = (const float*)d_in[3];
    const float* wb = (const float*)d_in[4];
    const float* lw = (const float*)d_in[5];
    const float* lb = (const float*)d_in[6];
    float* out = (float*)d_out;

    const int E = in_sizes[2];
    const int N = in_sizes[0] / 64;
    const int maxC = ((E + 63) >> 6) + NREL;

    char* p = (char*)d_ws;
    unsigned short* wtb = (unsigned short*)p;  p += (size_t)2 * NREL * 4096 * sizeof(unsigned short);
    unsigned short* xbf = (unsigned short*)p;  p += (size_t)N * 64 * sizeof(unsigned short);
    float* cntf = (float*)p;                   p += (size_t)N * sizeof(float);
    float* cntb = (float*)p;                   p += (size_t)N * sizeof(float);
    int*   hist = (int*)p;                     p += NREL * sizeof(int);
    int*   fill = (int*)p;                     p += NREL * sizeof(int);
    int*   bar  = (int*)p;                     p += 4 * sizeof(int);   // keep einfo 16B-aligned
    int4*  einfo = (int4*)p;                   p += (size_t)maxC * 64 * sizeof(int4);

    const int* srcp = ei;
    const int* dstp = ei + E;

    hipMemsetAsync(bar, 0, sizeof(int), stream);   // everything else zeroed in-kernel

    const int nCountB = (E + 255) / 256;
    const int nLinB   = (N + 31) / 32;
    // grid 768 = 3 blocks/CU x 256 CU; co-residency enforced by __launch_bounds__(256,3)
    fused_kernel<<<768, 256, 0, stream>>>(
        x, srcp, dstp, et, wf, wb, lw, lb,
        wtb, xbf, cntf, cntb, hist, fill, bar, einfo, out,
        E, N, nCountB, nLinB);
}

// Round 7
// 112.189 us; speedup vs baseline: 2.8482x; 2.8482x over previous
//
#include <hip/hip_runtime.h>

#define NREL 32

typedef short short8 __attribute__((ext_vector_type(8)));
typedef float f32x4 __attribute__((ext_vector_type(4)));

__device__ inline unsigned short f2bf(float f) {
    union { float f; unsigned u; } u; u.f = f;
    unsigned r = u.u + 0x7FFF + ((u.u >> 16) & 1);   // RNE
    return (unsigned short)(r >> 16);
}

// ---------------------------------------------------------------------------
// ws layout:
//   wtb  [2*32*4096] ushort  bf16 normalized tables, TRANSPOSED:
//                            wtb[(dir*32+r)*4096 + o*64 + i]
//   xbf  [N*64] ushort       bf16(x)
//   cntf [N] f32             # edges with src==n      (zeroed by memset)
//   cntb [N] f32             # edges with dst==n      (zeroed by memset)
//   fill [32] int            per-rel edge count / cursors (zeroed by memset)
//   einfo[32*CAP] int2       {src, dst} per edge, fixed-capacity rel buckets
// ---------------------------------------------------------------------------

// Fused independent setup: blocks [0,nCountB) count degrees + scatter into
// fixed-capacity rel buckets; [nCountB,nCountB+64) normalize+transpose
// weights; the rest do out = x@lin_w^T + b and write xbf = bf16(x).
__global__ __launch_bounds__(256) void setup_kernel(
        const float* __restrict__ x,
        const int* __restrict__ src, const int* __restrict__ dst,
        const int* __restrict__ et,
        const float* __restrict__ wf, const float* __restrict__ wb,
        const float* __restrict__ lw, const float* __restrict__ lb,
        float* __restrict__ cntf, float* __restrict__ cntb,
        int* __restrict__ fill, unsigned short* __restrict__ wtb,
        unsigned short* __restrict__ xbf, int2* __restrict__ einfo,
        float* __restrict__ out, int E, int N, int nCountB, int CAP) {
    __shared__ float smem[4 * 8 * 64 + 8];
    int tid = threadIdx.x;
    int b = blockIdx.x;

    if (b < nCountB) {
        // ---- count + scatter role (block-aggregated cursors) ----
        int* lh = (int*)smem;          // [0..31] per-rel block count
        int* lbase = lh + NREL;        // [32..63] reserved global base
        if (tid < 2 * NREL) lh[tid] = 0;
        __syncthreads();
        int e = b * 256 + tid;
        int s = 0, d = 0, r = 0, my = 0;
        bool valid = (e < E);
        if (valid) {
            s = src[e]; d = dst[e]; r = et[e];
            atomicAdd(&cntf[s], 1.0f);
            atomicAdd(&cntb[d], 1.0f);
            my = atomicAdd(&lh[r], 1);
        }
        __syncthreads();
        if (tid < NREL && lh[tid]) lbase[tid] = atomicAdd(&fill[tid], lh[tid]);
        __syncthreads();
        if (valid) einfo[r * CAP + lbase[r] + my] = make_int2(s, d);
        return;
    }
    b -= nCountB;
    if (b < 64) {
        // ---- norm role: normalize fp32 table row, write bf16 transposed ----
        int rel = b & 31, tab = b >> 5;
        const float* s_ = (tab ? wb : wf) + rel * 4096;
        unsigned short* d_ = wtb + (size_t)b * 4096;
        float* part = smem;
        float ssum = 0.f;
        #pragma unroll
        for (int k = 0; k < 16; k += 4) {
            float4 v = *(const float4*)(s_ + tid * 16 + k);
            ssum += v.x * v.x + v.y * v.y + v.z * v.z + v.w * v.w;
        }
        #pragma unroll
        for (int off = 32; off >= 1; off >>= 1) ssum += __shfl_down(ssum, off, 64);
        if ((tid & 63) == 0) part[tid >> 6] = ssum;
        __syncthreads();
        if (tid == 0) part[4] = 1.0f / (sqrtf(part[0] + part[1] + part[2] + part[3]) + 0.01f);
        __syncthreads();
        float sc = part[4];
        int i = tid >> 2, o0 = (tid & 3) * 16;
        #pragma unroll
        for (int q = 0; q < 4; ++q) {
            float4 v = *(const float4*)(s_ + i * 64 + o0 + q * 4);
            d_[(o0 + q * 4 + 0) * 64 + i] = f2bf(v.x * sc);
            d_[(o0 + q * 4 + 1) * 64 + i] = f2bf(v.y * sc);
            d_[(o0 + q * 4 + 2) * 64 + i] = f2bf(v.z * sc);
            d_[(o0 + q * 4 + 3) * 64 + i] = f2bf(v.w * sc);
        }
        return;
    }
    b -= 64;
    // ---- linear + xbf role: 32 nodes/block ----
    {
        int lane = tid & 63, w = tid >> 6;
        int nodeBase = b * 32 + w * 8;
        float4 wrow[16];
        const float4* lwrow = (const float4*)(lw + lane * 64);
        #pragma unroll
        for (int g = 0; g < 16; ++g) wrow[g] = lwrow[g];
        float bias = lb[lane];
        float* xs = smem + w * 8 * 64;
        #pragma unroll
        for (int t = 0; t < 8; ++t) {
            int n = nodeBase + t;
            if (n < N) {
                float v = x[(size_t)n * 64 + lane];
                xs[t * 64 + lane] = v;
                xbf[(size_t)n * 64 + lane] = f2bf(v);
            }
        }
        __syncthreads();
        for (int t = 0; t < 8; ++t) {
            int n = nodeBase + t;
            if (n >= N) break;
            float acc = bias;
            const float4* xr = (const float4*)(xs + t * 64);
            #pragma unroll
            for (int g = 0; g < 16; ++g) {
                float4 xv = xr[g];
                acc = fmaf(xv.x, wrow[g].x, acc);
                acc = fmaf(xv.y, wrow[g].y, acc);
                acc = fmaf(xv.z, wrow[g].z, acc);
                acc = fmaf(xv.w, wrow[g].w, acc);
            }
            out[(size_t)n * 64 + lane] = acc;
        }
    }
}

// One block per (64-edge chunk) x (direction = blockIdx.y). Bucket located
// from fill[] via in-register chunk-count scan + ballot.
#define APITCH 72  // 64 + 8 shorts pad
__global__ __launch_bounds__(256) void conv_mfma(
        const unsigned short* __restrict__ xbf,
        const float* __restrict__ cntf, const float* __restrict__ cntb,
        const int* __restrict__ fill,
        const unsigned short* __restrict__ wtb,
        const int2* __restrict__ einfo,
        float* __restrict__ out, int CAP) {
    int tid = threadIdx.x;
    int lane = tid & 63;

    // chunk-count scan over fill[32]
    int fr = (lane < NREL) ? fill[lane] : 0;
    int ch = (fr + 63) >> 6;
    int s_scan = ch;
    #pragma unroll
    for (int off = 1; off < 32; off <<= 1) {
        int t = __shfl_up(s_scan, off, 64);
        if ((lane & 31) >= off) s_scan += t;
    }
    int chExcl = s_scan - ch;

    int c = blockIdx.x;
    unsigned long long mm = __ballot(lane < NREL && c >= chExcl && c < chExcl + ch);
    if (mm == 0) return;                    // past last chunk (uniform)
    int rel = __ffsll(mm) - 1;
    int lc = c - __shfl(chExcl, rel, 64);
    int frr = __shfl(fr, rel, 64);
    int pos = rel * CAP + lc * 64;
    int valid = frr - lc * 64;
    if (valid > 64) valid = 64;
    int dir = blockIdx.y;

    __shared__ unsigned short As[64 * APITCH];  // As[j][i] = bf16(x[s_j][i])
    __shared__ unsigned short Bs[64 * APITCH];  // Bs[o][i] = Wn[i][o]
    __shared__ int dstS[64];
    __shared__ float invS[64];

    int j = tid >> 2, part = tid & 3;

    // stage B (transposed table is a straight copy)
    {
        const uint4* s4 = (const uint4*)(wtb + (size_t)((dir << 5) + rel) * 4096 + j * 64 + part * 16);
        uint4 v0 = s4[0], v1 = s4[1];
        *(uint4*)(&Bs[j * APITCH + part * 16]) = v0;
        *(uint4*)(&Bs[j * APITCH + part * 16 + 8]) = v1;
    }

    // stage A: bf16 row copy; 1/deg computed here (counts final by now)
    if (j >= valid) {
        uint4 z = {0, 0, 0, 0};
        *(uint4*)(&As[j * APITCH + part * 16]) = z;
        *(uint4*)(&As[j * APITCH + part * 16 + 8]) = z;
        if (part == 0) { dstS[j] = -1; invS[j] = 0.f; }
    } else {
        int2 v = einfo[pos + j];
        int s_ = dir ? v.y : v.x;
        int d_ = dir ? v.x : v.y;
        const uint4* xr = (const uint4*)(xbf + (size_t)s_ * 64);
        uint4 a0 = xr[part * 2], a1 = xr[part * 2 + 1];
        *(uint4*)(&As[j * APITCH + part * 16]) = a0;
        *(uint4*)(&As[j * APITCH + part * 16 + 8]) = a1;
        if (part == 0) {
            float cv = dir ? cntb[s_] : cntf[s_];
            dstS[j] = d_;
            invS[j] = 1.0f / (cv + 1.0f);
        }
    }
    __syncthreads();

    // MFMA: wave w computes edge rows [16w,16w+16) x all 64 out channels
    int w = tid >> 6;
    int m = lane & 15, quad = lane >> 4;
    f32x4 acc0 = {0.f, 0.f, 0.f, 0.f}, acc1 = acc0, acc2 = acc0, acc3 = acc0;
    #pragma unroll
    for (int k0 = 0; k0 < 64; k0 += 32) {
        short8 a  = *(const short8*)(&As[(w * 16 + m) * APITCH + k0 + quad * 8]);
        short8 b0 = *(const short8*)(&Bs[(0  + m) * APITCH + k0 + quad * 8]);
        short8 b1 = *(const short8*)(&Bs[(16 + m) * APITCH + k0 + quad * 8]);
        short8 b2 = *(const short8*)(&Bs[(32 + m) * APITCH + k0 + quad * 8]);
        short8 b3 = *(const short8*)(&Bs[(48 + m) * APITCH + k0 + quad * 8]);
        acc0 = __builtin_amdgcn_mfma_f32_16x16x32_bf16(a, b0, acc0, 0, 0, 0);
        acc1 = __builtin_amdgcn_mfma_f32_16x16x32_bf16(a, b1, acc1, 0, 0, 0);
        acc2 = __builtin_amdgcn_mfma_f32_16x16x32_bf16(a, b2, acc2, 0, 0, 0);
        acc3 = __builtin_amdgcn_mfma_f32_16x16x32_bf16(a, b3, acc3, 0, 0, 0);
    }

    // epilogue: C/D layout col=lane&15, row=quad*4+reg; scale by 1/deg in fp32
    int row_base = w * 16 + quad * 4;
    #pragma unroll
    for (int r = 0; r < 4; ++r) {
        int row = row_base + r;
        int d_ = dstS[row];
        if (d_ >= 0) {
            float inv = invS[row];
            float* op = out + (size_t)d_ * 64 + m;
            atomicAdd(op +  0, acc0[r] * inv);
            atomicAdd(op + 16, acc1[r] * inv);
            atomicAdd(op + 32, acc2[r] * inv);
            atomicAdd(op + 48, acc3[r] * inv);
        }
    }
}

extern "C" void kernel_launch(void* const* d_in, const int* in_sizes, int n_in,
                              void* d_out, int out_size, void* d_ws, size_t ws_size,
                              hipStream_t stream) {
    const float* x  = (const float*)d_in[0];
    const int*   ei = (const int*)  d_in[1];
    const int*   et = (const int*)  d_in[2];
    const float* wf = (const float*)d_in[3];
    const float* wb = (const float*)d_in[4];
    const float* lw = (const float*)d_in[5];
    const float* lb = (const float*)d_in[6];
    float* out = (float*)d_out;

    const int E = in_sizes[2];
    const int N = in_sizes[0] / 64;
    const int CAP = ((E + 63) >> 6) << 6;          // per-rel bucket capacity
    const int maxC = ((E + 63) >> 6) + NREL;       // upper bound on total chunks

    char* p = (char*)d_ws;
    unsigned short* wtb = (unsigned short*)p;  p += (size_t)2 * NREL * 4096 * sizeof(unsigned short);
    unsigned short* xbf = (unsigned short*)p;  p += (size_t)N * 64 * sizeof(unsigned short);
    float* cntf = (float*)p;                   p += (size_t)N * sizeof(float);
    float* cntb = (float*)p;                   p += (size_t)N * sizeof(float);
    int*   fill = (int*)p;                     p += NREL * sizeof(int);
    int2*  einfo = (int2*)p;                   p += (size_t)NREL * CAP * sizeof(int2);

    const int* srcp = ei;
    const int* dstp = ei + E;

    // zero cntf, cntb, fill (contiguous)
    hipMemsetAsync(cntf, 0, ((size_t)2 * N + NREL) * sizeof(float), stream);

    const int nCountB = (E + 255) / 256;
    const int nLinB   = (N + 31) / 32;
    setup_kernel<<<nCountB + 64 + nLinB, 256, 0, stream>>>(
        x, srcp, dstp, et, wf, wb, lw, lb, cntf, cntb, fill, wtb, xbf, einfo,
        out, E, N, nCountB, CAP);
    dim3 cgrid(maxC, 2);
    conv_mfma<<<cgrid, 256, 0, stream>>>(xbf, cntf, cntb, fill, wtb, einfo, out, CAP);
}